// Round 12
// baseline (117.033 us; speedup 1.0000x reference)
//
#include <hip/hip_runtime.h>
#include <math.h>

#define Bn 32
#define Rn 512
#define Dn 256
#define Pn 5532
#define MAXU 512

typedef short short8 __attribute__((ext_vector_type(8)));
typedef short short4v __attribute__((ext_vector_type(4)));
typedef float floatx4 __attribute__((ext_vector_type(4)));

// ---- workspace layout (4-byte words). sexp/nll/tickets zeroed by k1 blocks
// 33..49 each call; everything else read-after-write in-call (poison-safe).
#define XBF_OFF    0
#define XBF_WORDS  (Bn*Rn*Dn/2)
#define PBF_OFF    (XBF_OFF + XBF_WORDS)
#define PBF_WORDS  (Bn*MAXU*Dn/2)
#define LBLC_OFF   (PBF_OFF + PBF_WORDS)
#define CCNT_OFF   (LBLC_OFF + Bn*Rn)
#define CURS_OFF   (CCNT_OFF + Bn*MAXU)
#define RLIST_OFF  (CURS_OFF + Bn*MAXU)
#define NUNIQ_OFF  (RLIST_OFF + Bn*Rn)
#define NVALID_OFF (NUNIQ_OFF + 32)
#define SEXP_OFF   (NVALID_OFF + 32)
#define NLL_OFF    (SEXP_OFF + Bn*Rn)
#define TK2_OFF    (NLL_OFF + 1)
#define TICK_OFF   (TK2_OFF + 1)                     // 256 entries (b*8+rt)
#define ZEROW      (Bn*Rn + 2 + 256)                 // words starting at SEXP_OFF

__device__ __forceinline__ unsigned short bf16r(float f) {   // fp32 -> bf16 RNE
    union { float f; unsigned int u; } c; c.f = f;
    return (unsigned short)((c.u + 0x7FFFu + ((c.u >> 16) & 1u)) >> 16);
}

// async global->LDS, 16B per lane. LDS dest = wave-uniform base + lane*16.
__device__ __forceinline__ void async16(void* lds, const void* g) {
    auto* l3 = reinterpret_cast<__attribute__((address_space(3))) unsigned int*>(
                   reinterpret_cast<size_t>(lds));
    auto* g1 = reinterpret_cast<const __attribute__((address_space(1))) unsigned int*>(
                   reinterpret_cast<size_t>(g));
    __builtin_amdgcn_global_load_lds(g1, l3, 16, 0, 0);
}

// ==== k1: blocks 0..31 = in-LDS per-image compact; blocks 32..543 = convert+zero ====
__global__ __launch_bounds__(1024) void k1_prep(
    const float* __restrict__ inputs, const float* __restrict__ cls,
    const int* __restrict__ roi_label,
    unsigned short* __restrict__ xbf,
    int* __restrict__ lblc_arr, int* __restrict__ ccnt, int* __restrict__ cursor,
    int* __restrict__ rlist, int* __restrict__ nuniq, int* __restrict__ nvalid_arr,
    int* __restrict__ zbase)
{
    const int flat = blockIdx.x;
    const int t = threadIdx.x;

    __shared__ int cnt_lds[Pn];                       // 22.1 KB
    __shared__ int cmap_lds[Pn];                      // 22.1 KB
    __shared__ int curs_lds[MAXU];
    __shared__ int wpres[16], wcnt[16];

    if (flat >= 32) {
        // zero sexp + nll + ticket2 + tick[256] (blocks 33..49)
        if (flat >= 33 && flat <= 49) {
            int idx = (flat - 33) * 1024 + t;
            if (idx < ZEROW) zbase[idx] = 0;
        }
        // convert inputs*cls -> bf16: 512 blocks x 1024 thr x 8 elems
        int g = (flat - 32) * 1024 + t;               // 0..524287
        int e = g * 8;
        int row = e >> 8;                             // /Dn
        float cw = cls[row];
        float4 v0 = *(const float4*)&inputs[e];
        float4 v1 = *(const float4*)&inputs[e + 4];
        short8 o;
        o[0] = (short)bf16r(v0.x * cw); o[1] = (short)bf16r(v0.y * cw);
        o[2] = (short)bf16r(v0.z * cw); o[3] = (short)bf16r(v0.w * cw);
        o[4] = (short)bf16r(v1.x * cw); o[5] = (short)bf16r(v1.y * cw);
        o[6] = (short)bf16r(v1.z * cw); o[7] = (short)bf16r(v1.w * cw);
        *(short8*)&xbf[e] = o;
        return;
    }

    // ---- per-image compact: counts from this image's 512 labels, all in LDS ----
    const int b = flat;
    const int lane = t & 63, wid = t >> 6;            // 16 waves
    for (int i = t; i < Pn; i += 1024) cnt_lds[i] = 0;
    __syncthreads();
    int mylbl = -1;
    if (t < Rn) {
        mylbl = roi_label[b * Rn + t] - 1;
        if (mylbl >= 0) atomicAdd(&cnt_lds[mylbl], 1);
    }
    __syncthreads();

    int basePres = 0, baseCnt = 0;                    // replicated in all threads
    for (int i0 = 0; i0 < Pn; i0 += 1024) {           // 6 chunks
        int i = i0 + t;
        int cnt = (i < Pn) ? cnt_lds[i] : 0;
        bool pres = cnt > 0;
        unsigned long long mask = __ballot(pres);
        int pfx_pres = __popcll(mask & ((1ULL << lane) - 1ULL));
        int v = cnt;
        #pragma unroll
        for (int off = 1; off < 64; off <<= 1) {
            int u = __shfl_up(v, off);
            if (lane >= off) v += u;
        }
        int pfx_cnt = v - cnt;                        // exclusive
        if (lane == 63) { wpres[wid] = __popcll(mask); wcnt[wid] = v; }
        __syncthreads();
        int woffP = 0, totP = 0, woffC = 0, totC = 0;
        #pragma unroll
        for (int w = 0; w < 16; ++w) {
            int p = wpres[w], c = wcnt[w];
            if (w < wid) { woffP += p; woffC += c; }
            totP += p; totC += c;
        }
        if (pres) {
            int c = basePres + woffP + pfx_pres;      // compact slot < MAXU
            cmap_lds[i] = c;
            ccnt[b * MAXU + c] = cnt;
            curs_lds[c] = baseCnt + woffC + pfx_cnt;  // start offset
        }
        basePres += totP; baseCnt += totC;
        __syncthreads();
    }
    // per-roi compact label + scatter to global rlist via LDS cursors
    if (t < Rn) {
        int lc = (mylbl >= 0) ? cmap_lds[mylbl] : -1;
        lblc_arr[b * Rn + t] = lc;
        if (lc >= 0) {
            int pos = atomicAdd(&curs_lds[lc], 1);
            rlist[b * Rn + pos] = t;
        }
    }
    __syncthreads();
    if (t < MAXU && t < basePres)
        cursor[b * MAXU + t] = curs_lds[t];           // end offset (= start + cnt)
    if (t == 0) { nuniq[b] = basePres; nvalid_arr[b] = baseCnt; }
}

// ==== k2: gather -> mean -> L2 normalize -> bf16 proto (one slot per WAVE) ====
__global__ __launch_bounds__(256) void k2_proto(
    const float* __restrict__ inputs, const float* __restrict__ cls,
    const int* __restrict__ nuniq, const int* __restrict__ ccnt,
    const int* __restrict__ cursor, const int* __restrict__ rlist,
    unsigned short* __restrict__ pbf)
{
    const int lane = threadIdx.x & 63, wv = threadIdx.x >> 6;
    int s = blockIdx.x * 4 + wv;                      // 4096 blocks -> 16384 slots
    int b = s >> 9;
    int c = s & (MAXU - 1);
    if (c >= nuniq[b]) return;
    int cnt = ccnt[s];
    int start = cursor[s] - cnt;
    float4 acc = make_float4(0.f, 0.f, 0.f, 0.f);
    for (int k = 0; k < cnt; ++k) {
        int r = rlist[b * Rn + start + k];
        float cw = cls[b * Rn + r];
        float4 v = *(const float4*)&inputs[(size_t)(b * Rn + r) * Dn + lane * 4];
        acc.x += v.x * cw; acc.y += v.y * cw; acc.z += v.z * cw; acc.w += v.w * cw;
    }
    float inv = 1.0f / (float)cnt;
    acc.x *= inv; acc.y *= inv; acc.z *= inv; acc.w *= inv;
    float ss = acc.x*acc.x + acc.y*acc.y + acc.z*acc.z + acc.w*acc.w;
    #pragma unroll
    for (int off = 32; off > 0; off >>= 1) ss += __shfl_xor(ss, off);
    float scale = 1.0f / fmaxf(sqrtf(ss), 1e-12f);
    short4v o;
    o[0] = (short)bf16r(acc.x * scale); o[1] = (short)bf16r(acc.y * scale);
    o[2] = (short)bf16r(acc.z * scale); o[3] = (short)bf16r(acc.w * scale);
    *(short4v*)&pbf[(size_t)s * Dn + lane * 4] = o;
}

// ==== k3: bf16 MFMA GEMM (64x128 tile, 2048 blocks -> 4+/CU) + exp-sum merge ====
// Logits bounded (|x.p| <= |x| ~ 16, p unit) -> exp without max-subtraction is
// safe in fp32; Sum(exp) accumulates via device atomics (coherent path).
#define TRr 64
#define TCc 128
#define KCk 32

__global__ __launch_bounds__(256, 4) void k3_loss(
    const unsigned short* __restrict__ xbf, const unsigned short* __restrict__ pbf,
    const int* __restrict__ lblc_arr, const int* __restrict__ nuniq,
    float* __restrict__ sexp, float* __restrict__ nll,
    int* __restrict__ tick, int* __restrict__ ticket2,
    const int* __restrict__ nvalid_arr, float* __restrict__ out)
{
    // XOR-swizzled bf16 tiles (content group g at gpos = g ^ ((row>>1)&3)),
    // realized via per-lane GLOBAL address; LDS side stays lane*16-linear.
    __shared__ __align__(16) unsigned short xs[2][TRr * KCk];   // 2 x 4 KB
    __shared__ __align__(16) unsigned short ps[2][TCc * KCk];   // 2 x 8 KB
    __shared__ int lblc[TRr];
    __shared__ float msum[4];
    __shared__ int mflag;

    const int t = threadIdx.x;
    const int lane = t & 63, w = t >> 6;
    const int q = lane >> 4, r15 = lane & 15;
    const int rt = blockIdx.x;                        // 0..7
    const int b = blockIdx.y;
    const int pc = blockIdx.z;
    const int roiBase = rt * TRr;
    const int U = nuniq[b];
    const int nch = (U == 0) ? 1 : ((U + TCc - 1) >> 7);
    if (pc >= nch) return;                            // uniform block exit

    if (t < TRr) lblc[t] = lblc_arr[b * Rn + roiBase + t];

    // 12 chunks/stage: 0..3 = xs, 4..11 = ps; wave w stages {w, w+4, w+8}.
    const int s0 = w * 64 + lane;                     // x-chunk slot (chunk id w)
    const int xrow = s0 >> 2;
    const int xg = (s0 & 3) ^ ((xrow >> 1) & 3);
    const size_t xgbase = (size_t)(b * Rn + roiBase + xrow) * Dn + xg * 8;
    int prow[2], pg[2];
    #pragma unroll
    for (int cc = 0; cc < 2; ++cc) {
        int s = (w + cc * 4) * 64 + lane;             // p-chunks w, w+4 (of 8)
        prow[cc] = s >> 2;
        pg[cc] = (s & 3) ^ ((prow[cc] >> 1) & 3);
    }

    #define ISSUE(kc, buf)                                                        \
        do {                                                                      \
            async16(&xs[buf][w * 512], xbf + xgbase + (kc) * KCk);                \
            async16(&ps[buf][w * 512],                                            \
                    pbf + (size_t)(b * MAXU + pc * TCc + prow[0]) * Dn            \
                        + (kc) * KCk + pg[0] * 8);                                \
            async16(&ps[buf][(w + 4) * 512],                                      \
                    pbf + (size_t)(b * MAXU + pc * TCc + prow[1]) * Dn            \
                        + (kc) * KCk + pg[1] * 8);                                \
        } while (0)

    ISSUE(0, 0);

    floatx4 acc[4][2];
    #pragma unroll
    for (int mt = 0; mt < 4; ++mt)
        #pragma unroll
        for (int nt = 0; nt < 2; ++nt) acc[mt][nt] = (floatx4)0.f;

    for (int kc = 0; kc < Dn / KCk; ++kc) {           // 8 stages
        const int cur = kc & 1;
        __syncthreads();                              // buf[cur] resident
        if (kc < Dn / KCk - 1) ISSUE(kc + 1, cur ^ 1);

        short8 bb[2];
        #pragma unroll
        for (int nt = 0; nt < 2; ++nt) {
            int row = w * 32 + nt * 16 + r15;
            int off = row * KCk + ((q ^ ((row >> 1) & 3)) * 8);
            bb[nt] = *(const short8*)&ps[cur][off];
        }
        #pragma unroll
        for (int mt = 0; mt < 4; ++mt) {
            int row = mt * 16 + r15;
            int off = row * KCk + ((q ^ ((row >> 1) & 3)) * 8);
            short8 a = *(const short8*)&xs[cur][off];
            acc[mt][0] = __builtin_amdgcn_mfma_f32_16x16x32_bf16(a, bb[0], acc[mt][0], 0, 0, 0);
            acc[mt][1] = __builtin_amdgcn_mfma_f32_16x16x32_bf16(a, bb[1], acc[mt][1], 0, 0, 0);
        }
    }
    #undef ISSUE

    // ---- epilogue: exp-sum per roi + own-label dot; C/D: n=r15, m=q*4+reg ----
    const int c0 = pc * TCc + w * 32 + r15;
    const int c1 = c0 + 16;
    const bool v0 = c0 < U, v1 = c1 < U;
    float dsum = 0.f;
    #pragma unroll
    for (int mt = 0; mt < 4; ++mt)
        #pragma unroll
        for (int reg = 0; reg < 4; ++reg) {
            int mloc = mt * 16 + q * 4 + reg;
            float d0 = acc[mt][0][reg], d1 = acc[mt][1][reg];
            int lc = lblc[mloc];
            if (v0 && c0 == lc) dsum += d0;
            if (v1 && c1 == lc) dsum += d1;
            float es = (v0 ? __expf(d0) : 0.f) + (v1 ? __expf(d1) : 0.f);
            #pragma unroll
            for (int off = 1; off < 16; off <<= 1) es += __shfl_xor(es, off);
            if (r15 == 0) atomicAdd(&sexp[b * Rn + roiBase + mloc], es);
        }
    #pragma unroll
    for (int off = 1; off < 64; off <<= 1) dsum += __shfl_xor(dsum, off);
    if (lane == 0) msum[w] = dsum;
    __syncthreads();                                  // drains sexp atomics too
    if (t == 0) {
        atomicAdd(nll, -(msum[0] + msum[1] + msum[2] + msum[3]));
        __threadfence();                              // order vs ticket below
        int old = atomicAdd(&tick[b * 8 + rt], 1);
        mflag = (old == nch - 1);                     // last pc-sibling merges
    }
    __syncthreads();
    if (mflag) {
        float v = 0.f;
        if (t < TRr && lblc[t] >= 0)
            v = __logf(atomicAdd(&sexp[b * Rn + roiBase + t], 0.0f));  // coherent read
        #pragma unroll
        for (int off = 1; off < 64; off <<= 1) v += __shfl_xor(v, off);
        if (lane == 0) msum[w] = v;
        __syncthreads();
        if (t == 0) {
            atomicAdd(nll, msum[0] + msum[1] + msum[2] + msum[3]);
            __threadfence();
            int t2 = atomicAdd(ticket2, 1);
            if (t2 == 255) {                          // last of 256 groups finalizes
                float total = atomicAdd(nll, 0.0f);   // coherent read
                int nv = 0;
                for (int bb2 = 0; bb2 < Bn; ++bb2) nv += nvalid_arr[bb2];
                out[0] = total / fmaxf((float)nv, 1.0f);
            }
        }
    }
}

extern "C" void kernel_launch(void* const* d_in, const int* in_sizes, int n_in,
                              void* d_out, int out_size, void* d_ws, size_t ws_size,
                              hipStream_t stream) {
    const float* inputs = (const float*)d_in[0];
    const float* cls    = (const float*)d_in[1];
    const int*   roi    = (const int*)d_in[2];
    float* out = (float*)d_out;

    float* wsf = (float*)d_ws;
    int*   wsi = (int*)d_ws;
    unsigned short* xbf = (unsigned short*)(wsi + XBF_OFF);
    unsigned short* pbf = (unsigned short*)(wsi + PBF_OFF);
    int*   lblc   = wsi + LBLC_OFF;
    int*   ccnt   = wsi + CCNT_OFF;
    int*   cursor = wsi + CURS_OFF;
    int*   rlist  = wsi + RLIST_OFF;
    int*   nuniq  = wsi + NUNIQ_OFF;
    int*   nvalid = wsi + NVALID_OFF;
    float* sexp   = wsf + SEXP_OFF;
    float* nll    = wsf + NLL_OFF;
    int*   tk2    = wsi + TK2_OFF;
    int*   tick   = wsi + TICK_OFF;

    k1_prep<<<32 + 512, 1024, 0, stream>>>(inputs, cls, roi, xbf, lblc, ccnt,
                                           cursor, rlist, nuniq, nvalid,
                                           wsi + SEXP_OFF);
    k2_proto<<<(Bn * MAXU) / 4, 256, 0, stream>>>(inputs, cls, nuniq, ccnt, cursor,
                                                  rlist, pbf);
    dim3 g(Rn / TRr, Bn, 4);
    k3_loss<<<g, 256, 0, stream>>>(xbf, pbf, lblc, nuniq, sexp, nll, tick, tk2,
                                   nvalid, out);
}

// Round 13
// 101.913 us; speedup vs baseline: 1.1484x; 1.1484x over previous
//
#include <hip/hip_runtime.h>
#include <math.h>

#define Bn 32
#define Rn 512
#define Dn 256
#define Pn 5532
#define MAXU 512

typedef short short8 __attribute__((ext_vector_type(8)));
typedef short short4v __attribute__((ext_vector_type(4)));
typedef float floatx4 __attribute__((ext_vector_type(4)));

// ---- workspace layout (4-byte words). sexp/nll/tickets zeroed by k1 blocks
// 33..49 each call; everything else read-after-write in-call (poison-safe).
#define XBF_OFF    0
#define XBF_WORDS  (Bn*Rn*Dn/2)
#define PBF_OFF    (XBF_OFF + XBF_WORDS)
#define PBF_WORDS  (Bn*MAXU*Dn/2)
#define LBLC_OFF   (PBF_OFF + PBF_WORDS)
#define CCNT_OFF   (LBLC_OFF + Bn*Rn)
#define CURS_OFF   (CCNT_OFF + Bn*MAXU)
#define RLIST_OFF  (CURS_OFF + Bn*MAXU)
#define NUNIQ_OFF  (RLIST_OFF + Bn*Rn)
#define NVALID_OFF (NUNIQ_OFF + 32)
#define SEXP_OFF   (NVALID_OFF + 32)
#define NLL_OFF    (SEXP_OFF + Bn*Rn)
#define TK2_OFF    (NLL_OFF + 1)
#define TICK_OFF   (TK2_OFF + 1)                     // 128 entries (b*4+rt)
#define ZEROW      (Bn*Rn + 2 + 128)                 // words starting at SEXP_OFF

__device__ __forceinline__ unsigned short bf16r(float f) {   // fp32 -> bf16 RNE
    union { float f; unsigned int u; } c; c.f = f;
    return (unsigned short)((c.u + 0x7FFFu + ((c.u >> 16) & 1u)) >> 16);
}
__device__ __forceinline__ float bfu2f(unsigned int hi16) {  // <<16'd bf16 -> f32
    union { unsigned int u; float f; } c; c.u = hi16;
    return c.f;
}

// async global->LDS, 16B per lane. LDS dest = wave-uniform base + lane*16.
__device__ __forceinline__ void async16(void* lds, const void* g) {
    auto* l3 = reinterpret_cast<__attribute__((address_space(3))) unsigned int*>(
                   reinterpret_cast<size_t>(lds));
    auto* g1 = reinterpret_cast<const __attribute__((address_space(1))) unsigned int*>(
                   reinterpret_cast<size_t>(g));
    __builtin_amdgcn_global_load_lds(g1, l3, 16, 0, 0);
}

// ==== k1: blocks 0..31 = in-LDS per-image compact; blocks 32..543 = convert+zero ====
__global__ __launch_bounds__(1024) void k1_prep(
    const float* __restrict__ inputs, const float* __restrict__ cls,
    const int* __restrict__ roi_label,
    unsigned short* __restrict__ xbf,
    int* __restrict__ lblc_arr, int* __restrict__ ccnt, int* __restrict__ cursor,
    int* __restrict__ rlist, int* __restrict__ nuniq, int* __restrict__ nvalid_arr,
    int* __restrict__ zbase)
{
    const int flat = blockIdx.x;
    const int t = threadIdx.x;

    __shared__ int cnt_lds[Pn];                       // 22.1 KB
    __shared__ int cmap_lds[Pn];                      // 22.1 KB
    __shared__ int curs_lds[MAXU];
    __shared__ int wpres[16], wcnt[16];

    if (flat >= 32) {
        // zero sexp + nll + ticket2 + tick[128] (blocks 33..49)
        if (flat >= 33 && flat <= 49) {
            int idx = (flat - 33) * 1024 + t;
            if (idx < ZEROW) zbase[idx] = 0;
        }
        // convert inputs*cls -> bf16: 512 blocks x 1024 thr x 8 elems
        int g = (flat - 32) * 1024 + t;               // 0..524287
        int e = g * 8;
        int row = e >> 8;                             // /Dn
        float cw = cls[row];
        float4 v0 = *(const float4*)&inputs[e];
        float4 v1 = *(const float4*)&inputs[e + 4];
        short8 o;
        o[0] = (short)bf16r(v0.x * cw); o[1] = (short)bf16r(v0.y * cw);
        o[2] = (short)bf16r(v0.z * cw); o[3] = (short)bf16r(v0.w * cw);
        o[4] = (short)bf16r(v1.x * cw); o[5] = (short)bf16r(v1.y * cw);
        o[6] = (short)bf16r(v1.z * cw); o[7] = (short)bf16r(v1.w * cw);
        *(short8*)&xbf[e] = o;
        return;
    }

    // ---- per-image compact: counts from this image's 512 labels, all in LDS ----
    const int b = flat;
    const int lane = t & 63, wid = t >> 6;            // 16 waves
    for (int i = t; i < Pn; i += 1024) cnt_lds[i] = 0;
    __syncthreads();
    int mylbl = -1;
    if (t < Rn) {
        mylbl = roi_label[b * Rn + t] - 1;
        if (mylbl >= 0) atomicAdd(&cnt_lds[mylbl], 1);
    }
    __syncthreads();

    int basePres = 0, baseCnt = 0;                    // replicated in all threads
    for (int i0 = 0; i0 < Pn; i0 += 1024) {           // 6 chunks
        int i = i0 + t;
        int cnt = (i < Pn) ? cnt_lds[i] : 0;
        bool pres = cnt > 0;
        unsigned long long mask = __ballot(pres);
        int pfx_pres = __popcll(mask & ((1ULL << lane) - 1ULL));
        int v = cnt;
        #pragma unroll
        for (int off = 1; off < 64; off <<= 1) {
            int u = __shfl_up(v, off);
            if (lane >= off) v += u;
        }
        int pfx_cnt = v - cnt;                        // exclusive
        if (lane == 63) { wpres[wid] = __popcll(mask); wcnt[wid] = v; }
        __syncthreads();
        int woffP = 0, totP = 0, woffC = 0, totC = 0;
        #pragma unroll
        for (int w = 0; w < 16; ++w) {
            int p = wpres[w], c = wcnt[w];
            if (w < wid) { woffP += p; woffC += c; }
            totP += p; totC += c;
        }
        if (pres) {
            int c = basePres + woffP + pfx_pres;      // compact slot < MAXU
            cmap_lds[i] = c;
            ccnt[b * MAXU + c] = cnt;
            curs_lds[c] = baseCnt + woffC + pfx_cnt;  // start offset
        }
        basePres += totP; baseCnt += totC;
        __syncthreads();
    }
    // per-roi compact label + scatter to global rlist via LDS cursors
    if (t < Rn) {
        int lc = (mylbl >= 0) ? cmap_lds[mylbl] : -1;
        lblc_arr[b * Rn + t] = lc;
        if (lc >= 0) {
            int pos = atomicAdd(&curs_lds[lc], 1);
            rlist[b * Rn + pos] = t;
        }
    }
    __syncthreads();
    if (t < MAXU && t < basePres)
        cursor[b * MAXU + t] = curs_lds[t];           // end offset (= start + cnt)
    if (t == 0) { nuniq[b] = basePres; nvalid_arr[b] = baseCnt; }
}

// ==== k2: gather (bf16 xbf) -> mean -> L2 normalize -> bf16 proto (slot/WAVE) ====
__global__ __launch_bounds__(256) void k2_proto(
    const unsigned short* __restrict__ xbf,
    const int* __restrict__ nuniq, const int* __restrict__ ccnt,
    const int* __restrict__ cursor, const int* __restrict__ rlist,
    unsigned short* __restrict__ pbf)
{
    const int lane = threadIdx.x & 63, wv = threadIdx.x >> 6;
    int s = blockIdx.x * 4 + wv;                      // 4096 blocks -> 16384 slots
    int b = s >> 9;
    int c = s & (MAXU - 1);
    if (c >= nuniq[b]) return;
    int cnt = ccnt[s];
    int start = cursor[s] - cnt;
    float a0 = 0.f, a1 = 0.f, a2 = 0.f, a3 = 0.f;
    for (int k = 0; k < cnt; ++k) {
        int r = rlist[b * Rn + start + k];
        uint2 pk = *(const uint2*)&xbf[((size_t)(b * Rn + r)) * Dn + lane * 4];
        a0 += bfu2f(pk.x << 16); a1 += bfu2f(pk.x & 0xFFFF0000u);
        a2 += bfu2f(pk.y << 16); a3 += bfu2f(pk.y & 0xFFFF0000u);
    }
    float inv = 1.0f / (float)cnt;
    a0 *= inv; a1 *= inv; a2 *= inv; a3 *= inv;
    float ss = a0*a0 + a1*a1 + a2*a2 + a3*a3;
    #pragma unroll
    for (int off = 32; off > 0; off >>= 1) ss += __shfl_xor(ss, off);
    float scale = 1.0f / fmaxf(sqrtf(ss), 1e-12f);
    short4v o;
    o[0] = (short)bf16r(a0 * scale); o[1] = (short)bf16r(a1 * scale);
    o[2] = (short)bf16r(a2 * scale); o[3] = (short)bf16r(a3 * scale);
    *(short4v*)&pbf[(size_t)s * Dn + lane * 4] = o;
}

// ==== k3: bf16 MFMA GEMM (128x128 tile, R11-proven) + exp-sum ticketed merge ====
// Logits bounded (|x.p| <= |x| ~ 16, p unit) -> exp without max-subtraction is
// safe in fp32; Sum(exp) accumulates via device atomics (coherent path).
#define TRr 128
#define TCc 128
#define KCk 32

__global__ __launch_bounds__(256, 3) void k3_loss(
    const unsigned short* __restrict__ xbf, const unsigned short* __restrict__ pbf,
    const int* __restrict__ lblc_arr, const int* __restrict__ nuniq,
    float* __restrict__ sexp, float* __restrict__ nll,
    int* __restrict__ tick, int* __restrict__ ticket2,
    const int* __restrict__ nvalid_arr, float* __restrict__ out)
{
    // XOR-swizzled bf16 tiles (content group g at gpos = g ^ ((row>>1)&3)),
    // realized via per-lane GLOBAL address; LDS side stays lane*16-linear.
    __shared__ __align__(16) unsigned short xs[2][TRr * KCk];   // 2 x 8 KB
    __shared__ __align__(16) unsigned short ps[2][TCc * KCk];   // 2 x 8 KB
    __shared__ int lblc[TRr];
    __shared__ float msum[4];
    __shared__ int mflag;

    const int t = threadIdx.x;
    const int lane = t & 63, w = t >> 6;
    const int q = lane >> 4, r15 = lane & 15;
    const int rt = blockIdx.x;
    const int b = blockIdx.y;
    const int pc = blockIdx.z;
    const int roiBase = rt * TRr;
    const int U = nuniq[b];
    const int nch = (U == 0) ? 1 : ((U + TCc - 1) >> 7);
    if (pc >= nch) return;                            // uniform block exit

    if (t < TRr) lblc[t] = lblc_arr[b * Rn + roiBase + t];

    // 16 chunks/stage (8 xs + 8 ps); wave w stages xs {w, w+4}, ps {w, w+4}.
    int xrow[2], xg[2];
    #pragma unroll
    for (int cc = 0; cc < 2; ++cc) {
        int s = (w + cc * 4) * 64 + lane;
        xrow[cc] = s >> 2; xg[cc] = (s & 3) ^ ((xrow[cc] >> 1) & 3);
    }

    #define ISSUE(kc, buf)                                                         \
        do {                                                                       \
            async16(&xs[buf][w * 512],                                             \
                    xbf + (size_t)(b * Rn + roiBase + xrow[0]) * Dn                \
                        + (kc) * KCk + xg[0] * 8);                                 \
            async16(&xs[buf][(w + 4) * 512],                                       \
                    xbf + (size_t)(b * Rn + roiBase + xrow[1]) * Dn                \
                        + (kc) * KCk + xg[1] * 8);                                 \
            async16(&ps[buf][w * 512],                                             \
                    pbf + (size_t)(b * MAXU + pc * TCc + xrow[0]) * Dn             \
                        + (kc) * KCk + xg[0] * 8);                                 \
            async16(&ps[buf][(w + 4) * 512],                                       \
                    pbf + (size_t)(b * MAXU + pc * TCc + xrow[1]) * Dn             \
                        + (kc) * KCk + xg[1] * 8);                                 \
        } while (0)

    ISSUE(0, 0);

    floatx4 acc[8][2];
    #pragma unroll
    for (int mt = 0; mt < 8; ++mt)
        #pragma unroll
        for (int nt = 0; nt < 2; ++nt) acc[mt][nt] = (floatx4)0.f;

    for (int kc = 0; kc < Dn / KCk; ++kc) {           // 8 stages
        const int cur = kc & 1;
        __syncthreads();                              // buf[cur] resident
        if (kc < Dn / KCk - 1) ISSUE(kc + 1, cur ^ 1);

        short8 bb[2];
        #pragma unroll
        for (int nt = 0; nt < 2; ++nt) {
            int row = w * 32 + nt * 16 + r15;
            int off = row * KCk + ((q ^ ((row >> 1) & 3)) * 8);
            bb[nt] = *(const short8*)&ps[cur][off];
        }
        #pragma unroll
        for (int mt = 0; mt < 8; ++mt) {
            int row = mt * 16 + r15;
            int off = row * KCk + ((q ^ ((row >> 1) & 3)) * 8);
            short8 a = *(const short8*)&xs[cur][off];
            acc[mt][0] = __builtin_amdgcn_mfma_f32_16x16x32_bf16(a, bb[0], acc[mt][0], 0, 0, 0);
            acc[mt][1] = __builtin_amdgcn_mfma_f32_16x16x32_bf16(a, bb[1], acc[mt][1], 0, 0, 0);
        }
    }
    #undef ISSUE

    // ---- epilogue: exp-sum per roi + own-label dot; C/D: n=r15, m=q*4+reg ----
    const int c0 = pc * TCc + w * 32 + r15;
    const int c1 = c0 + 16;
    const bool v0 = c0 < U, v1 = c1 < U;
    float dsum = 0.f;
    #pragma unroll
    for (int mt = 0; mt < 8; ++mt)
        #pragma unroll
        for (int reg = 0; reg < 4; ++reg) {
            int mloc = mt * 16 + q * 4 + reg;
            float d0 = acc[mt][0][reg], d1 = acc[mt][1][reg];
            int lc = lblc[mloc];
            if (v0 && c0 == lc) dsum += d0;
            if (v1 && c1 == lc) dsum += d1;
            float es = (v0 ? __expf(d0) : 0.f) + (v1 ? __expf(d1) : 0.f);
            #pragma unroll
            for (int off = 1; off < 16; off <<= 1) es += __shfl_xor(es, off);
            if (r15 == 0) atomicAdd(&sexp[b * Rn + roiBase + mloc], es);
        }
    #pragma unroll
    for (int off = 1; off < 64; off <<= 1) dsum += __shfl_xor(dsum, off);
    if (lane == 0) msum[w] = dsum;
    __syncthreads();                                  // drains sexp atomics too
    if (t == 0) {
        atomicAdd(nll, -(msum[0] + msum[1] + msum[2] + msum[3]));
        __threadfence();                              // order vs ticket below
        int old = atomicAdd(&tick[b * 4 + rt], 1);
        mflag = (old == nch - 1);                     // last pc-sibling merges
    }
    __syncthreads();
    if (mflag) {
        float v = 0.f;
        if (t < TRr && lblc[t] >= 0)
            v = __logf(atomicAdd(&sexp[b * Rn + roiBase + t], 0.0f));  // coherent read
        #pragma unroll
        for (int off = 1; off < 64; off <<= 1) v += __shfl_xor(v, off);
        if (lane == 0) msum[w] = v;
        __syncthreads();
        if (t == 0) {
            atomicAdd(nll, msum[0] + msum[1] + msum[2] + msum[3]);
            __threadfence();
            int t2 = atomicAdd(ticket2, 1);
            if (t2 == 127) {                          // last of 128 groups finalizes
                float total = atomicAdd(nll, 0.0f);   // coherent read
                int nv = 0;
                for (int bb2 = 0; bb2 < Bn; ++bb2) nv += nvalid_arr[bb2];
                out[0] = total / fmaxf((float)nv, 1.0f);
            }
        }
    }
}

extern "C" void kernel_launch(void* const* d_in, const int* in_sizes, int n_in,
                              void* d_out, int out_size, void* d_ws, size_t ws_size,
                              hipStream_t stream) {
    const float* inputs = (const float*)d_in[0];
    const float* cls    = (const float*)d_in[1];
    const int*   roi    = (const int*)d_in[2];
    float* out = (float*)d_out;

    float* wsf = (float*)d_ws;
    int*   wsi = (int*)d_ws;
    unsigned short* xbf = (unsigned short*)(wsi + XBF_OFF);
    unsigned short* pbf = (unsigned short*)(wsi + PBF_OFF);
    int*   lblc   = wsi + LBLC_OFF;
    int*   ccnt   = wsi + CCNT_OFF;
    int*   cursor = wsi + CURS_OFF;
    int*   rlist  = wsi + RLIST_OFF;
    int*   nuniq  = wsi + NUNIQ_OFF;
    int*   nvalid = wsi + NVALID_OFF;
    float* sexp   = wsf + SEXP_OFF;
    float* nll    = wsf + NLL_OFF;
    int*   tk2    = wsi + TK2_OFF;
    int*   tick   = wsi + TICK_OFF;

    k1_prep<<<32 + 512, 1024, 0, stream>>>(inputs, cls, roi, xbf, lblc, ccnt,
                                           cursor, rlist, nuniq, nvalid,
                                           wsi + SEXP_OFF);
    k2_proto<<<(Bn * MAXU) / 4, 256, 0, stream>>>(xbf, nuniq, ccnt, cursor,
                                                  rlist, pbf);
    dim3 g(Rn / TRr, Bn, 4);
    k3_loss<<<g, 256, 0, stream>>>(xbf, pbf, lblc, nuniq, sexp, nll, tick, tk2,
                                   nvalid, out);
}